// Round 5
// baseline (163.918 us; speedup 1.0000x reference)
//
#include <hip/hip_runtime.h>
#include <hip/hip_bf16.h>
#include <hip/hip_fp16.h>

// Encoder: neigh_feats = mean(raw[idx], axis=1); x = nf @ W; BN(train); LeakyReLU(0.01)
// Inputs: raw[100000,128]f32, W[128,128]f32, gamma[128], beta[128], idx[50000,16]i32
// Output: [50000,128] f32
//
// R5 == R4 with the enc_mm tile-distribution bug fixed: all 4 waves of a block
// process the SAME tile (wave wv owns columns [wv*32, wv*32+32)). R4 gave each
// wave its own tile -> 96/128 columns never written.
// Pipeline:
//   enc_conv:   raw f32 -> rawh f16 (256B rows), W -> Wt f16 transposed, zero stats
//   enc_gather: barrier-free, LDS-free gather+mean -> nf f16 (packed v_pk_add_f16)
//   enc_mm:     MFMA f16 GEMM, A-frags direct from global row-major nf; B in regs
//   enc_bn:     in-place BN+LeakyReLU on f32 d_out
// f32 fallback path if ws too small.

#define NTOTAL 100000
#define FEAT   128
#define NB     50000
#define KNEI   16
#define NTILES (NB / 16)   // 3125

// ws layout
#define OFF_STATS 0
#define OFF_WT    1024
#define OFF_RAWH  33792
#define OFF_NF    (33792 + 25600000)
#define WS_NEEDED (OFF_NF + 12800000)   // 38433792 B

typedef float f32x4 __attribute__((ext_vector_type(4)));
typedef short bf16x8 __attribute__((ext_vector_type(8)));
typedef _Float16 f16x8 __attribute__((ext_vector_type(8)));

__device__ __forceinline__ unsigned short f2bf(float f) {
    union { float f; unsigned u; } v; v.f = f;
    unsigned r = v.u + 0x7FFF + ((v.u >> 16) & 1);
    return (unsigned short)(r >> 16);
}

__device__ __forceinline__ unsigned h2add(unsigned a, unsigned b) {
    union { unsigned u; __half2 h; } x, y, r;
    x.u = a; y.u = b; r.h = __hadd2(x.h, y.h);
    return r.u;
}
__device__ __forceinline__ unsigned h2scale16(unsigned a) {   // * 0.0625
    union { unsigned u; __half2 h; } x, c, r;
    x.u = a; c.u = 0x2C002C00u;   // (0.0625, 0.0625) f16
    r.h = __hmul2(x.h, c.h);
    return r.u;
}

// ---- conv: raw f32 -> f16, W -> Wt f16 transposed (Wt[n*128+k]=W[k][n]), stats=0
__global__ __launch_bounds__(256) void enc_conv(
    const float* __restrict__ raw, const float* __restrict__ W,
    unsigned short* __restrict__ rawh, unsigned short* __restrict__ Wt,
    float* __restrict__ gstats)
{
    const int t = threadIdx.x;
    if (blockIdx.x < 64) {
        int e = blockIdx.x * 256 + t;     // 0..16383
        int n = e >> 7, k = e & 127;
        union { unsigned short s; __half h; } c; c.h = __float2half(W[k * FEAT + n]);
        Wt[e] = c.s;
    }
    if (blockIdx.x == 64 && t < 2 * FEAT) gstats[t] = 0.f;

    const float4* raw4 = (const float4*)raw;
    uint2* rh = (uint2*)rawh;
    const int NQ = NTOTAL * FEAT / 4;     // 3.2M
    for (int e = blockIdx.x * 256 + t; e < NQ; e += gridDim.x * 256) {
        float4 v = raw4[e];
        union { unsigned u; __half2 h; } lo, hi;
        lo.h = __float22half2_rn(make_float2(v.x, v.y));
        hi.h = __float22half2_rn(make_float2(v.z, v.w));
        uint2 o; o.x = lo.u; o.y = hi.u;
        rh[e] = o;
    }
}

// ---- gather: barrier-free mean over 16 neighbors, f16 in / f16 out --------------
// thread = (row, 16B-chunk). Wave: 4 rows x 16 chunks; per load-instr the wave
// reads 4 random 256B rows fully coalesced. 16 loads outstanding per thread.
__global__ __launch_bounds__(256, 5) void enc_gather(
    const unsigned short* __restrict__ rawh, const int* __restrict__ idx,
    unsigned short* __restrict__ nf)
{
    const int t = threadIdx.x;
    const int lane = t & 63;
    const int w = (blockIdx.x * 256 + t) >> 6;   // global wave 0..12499
    const int r0 = w * 4;                        // 4 rows per wave
    const int s = lane >> 4, c = lane & 15;

    const int iv = idx[r0 * KNEI + lane];        // this wave's 64 indices, coalesced

    uint4 v[16];
    #pragma unroll
    for (int k = 0; k < KNEI; ++k) {
        int ik = __shfl(iv, s * 16 + k);         // idx[(r0+s)*16 + k]
        v[k] = *(const uint4*)&rawh[(size_t)ik * FEAT + c * 8];
    }
    // pairwise tree sum in packed f16
    #pragma unroll
    for (int st = 8; st >= 1; st >>= 1) {
        #pragma unroll
        for (int k = 0; k < 8; ++k) {
            if (k < st) {
                v[k].x = h2add(v[k].x, v[k + st].x);
                v[k].y = h2add(v[k].y, v[k + st].y);
                v[k].z = h2add(v[k].z, v[k + st].z);
                v[k].w = h2add(v[k].w, v[k + st].w);
            }
        }
    }
    uint4 o;
    o.x = h2scale16(v[0].x); o.y = h2scale16(v[0].y);
    o.z = h2scale16(v[0].z); o.w = h2scale16(v[0].w);
    *(uint4*)&nf[(size_t)(r0 + s) * FEAT + c * 8] = o;
}

// ---- mm: x = nf @ W via MFMA f16; A-frags direct from global; stats ------------
// ALL 4 waves of a block process the same tile; wave wv owns n in [wv*32, wv*32+32).
__global__ __launch_bounds__(256, 4) void enc_mm(
    const unsigned short* __restrict__ nf, const unsigned short* __restrict__ Wt,
    float* __restrict__ out, float* __restrict__ gstats)
{
    const int t = threadIdx.x;
    const int lane = t & 63;
    const int wv = t >> 6;
    const int ln = lane & 15, qd = lane >> 4;
    const int n0 = wv * 32 + ln, n1 = n0 + 16;

    f16x8 b0[4], b1[4];
    #pragma unroll
    for (int kt = 0; kt < 4; ++kt) {
        const int k0 = kt * 32 + qd * 8;
        b0[kt] = *(const f16x8*)&Wt[n0 * FEAT + k0];
        b1[kt] = *(const f16x8*)&Wt[n1 * FEAT + k0];
    }

    float s1a = 0.f, s2a = 0.f, s1b = 0.f, s2b = 0.f;

    for (int tile = blockIdx.x; tile < NTILES; tile += gridDim.x) {
        const int i0 = tile * 16;
        f32x4 acc0 = {0.f, 0.f, 0.f, 0.f}, acc1 = {0.f, 0.f, 0.f, 0.f};
        #pragma unroll
        for (int kt = 0; kt < 4; ++kt) {
            const int k0 = kt * 32 + qd * 8;
            f16x8 a = *(const f16x8*)&nf[(size_t)(i0 + ln) * FEAT + k0];
            acc0 = __builtin_amdgcn_mfma_f32_16x16x32_f16(a, b0[kt], acc0, 0, 0, 0);
            acc1 = __builtin_amdgcn_mfma_f32_16x16x32_f16(a, b1[kt], acc1, 0, 0, 0);
        }
        #pragma unroll
        for (int ri = 0; ri < 4; ++ri) {
            const int row = i0 + qd * 4 + ri;
            float v0 = acc0[ri], v1 = acc1[ri];
            out[row * FEAT + n0] = v0;
            out[row * FEAT + n1] = v1;
            s1a += v0; s2a += v0 * v0;
            s1b += v1; s2b += v1 * v1;
        }
    }

    s1a += __shfl_down(s1a, 32); s1a += __shfl_down(s1a, 16);
    s2a += __shfl_down(s2a, 32); s2a += __shfl_down(s2a, 16);
    s1b += __shfl_down(s1b, 32); s1b += __shfl_down(s1b, 16);
    s2b += __shfl_down(s2b, 32); s2b += __shfl_down(s2b, 16);
    if (qd == 0) {
        atomicAdd(&gstats[n0], s1a);
        atomicAdd(&gstats[FEAT + n0], s2a);
        atomicAdd(&gstats[n1], s1b);
        atomicAdd(&gstats[FEAT + n1], s2b);
    }
}

// ---- bn: in-place BN + LeakyReLU on f32 out ------------------------------------
__global__ __launch_bounds__(256) void enc_bn(
    float* __restrict__ out, const float* __restrict__ gstats,
    const float* __restrict__ gamma, const float* __restrict__ beta)
{
    __shared__ float sScale[FEAT], sShift[FEAT];
    const int t = threadIdx.x;
    if (t < FEAT) {
        float s1 = gstats[t], s2 = gstats[FEAT + t];
        float mean = s1 * (1.0f / NB);
        float var = s2 * (1.0f / NB) - mean * mean;
        float sc = gamma[t] * rsqrtf(var + 1e-5f);
        sScale[t] = sc;
        sShift[t] = beta[t] - mean * sc;
    }
    __syncthreads();
    const int f4 = (t & 31) * 4;    // thread-invariant feature quad
    const float4 sc = *(const float4*)&sScale[f4];
    const float4 sh = *(const float4*)&sShift[f4];
    const int total4 = NB * FEAT / 4;
    float4* o4 = (float4*)out;
    for (int e = blockIdx.x * 256 + t; e < total4; e += gridDim.x * 256) {
        float4 v = o4[e];
        float4 r; float y;
        y = v.x * sc.x + sh.x; r.x = (y >= 0.f) ? y : 0.01f * y;
        y = v.y * sc.y + sh.y; r.y = (y >= 0.f) ? y : 0.01f * y;
        y = v.z * sc.z + sh.z; r.z = (y >= 0.f) ? y : 0.01f * y;
        y = v.w * sc.w + sh.w; r.w = (y >= 0.f) ? y : 0.01f * y;
        o4[e] = r;
    }
}

// ======================= fallback (f32 path, R1-proven) =========================
#define WT_LD 136
#define A_LD  136
__global__ __launch_bounds__(256, 4) void enc_gemm_f(
    const float* __restrict__ raw, const float* __restrict__ W,
    const int* __restrict__ idx, float* __restrict__ out,
    float* __restrict__ gstats)
{
    __shared__ unsigned short sWt[128 * WT_LD];
    __shared__ unsigned short sA[16 * A_LD];
    __shared__ int sidx[256];
    const int t = threadIdx.x;
    #pragma unroll 4
    for (int i = 0; i < 64; ++i) {
        int e = t + i * 256;
        int f = e >> 7, n = e & 127;
        sWt[n * WT_LD + f] = f2bf(W[e]);
    }
    const int lane = t & 63, wv = t >> 6, ln = lane & 15, qd = lane >> 4;
    const int c = t & 31, g = t >> 5;
    const int n0 = wv * 32 + ln, n1 = n0 + 16;
    float s1a = 0.f, s2a = 0.f, s1b = 0.f, s2b = 0.f;
    const float4* raw4 = (const float4*)raw;
    for (int tile = blockIdx.x; tile < NTILES; tile += gridDim.x) {
        const int i0 = tile * 16;
        __syncthreads();
        sidx[t] = idx[i0 * KNEI + t];
        __syncthreads();
        #pragma unroll
        for (int rr = 0; rr < 2; ++rr) {
            const int r = g * 2 + rr;
            const int* ip = &sidx[r * KNEI];
            float4 acc = {0.f, 0.f, 0.f, 0.f};
            #pragma unroll
            for (int k = 0; k < KNEI; ++k) {
                float4 v = raw4[(size_t)ip[k] * 32 + c];
                acc.x += v.x; acc.y += v.y; acc.z += v.z; acc.w += v.w;
            }
            ushort4 b;
            b.x = f2bf(acc.x * 0.0625f); b.y = f2bf(acc.y * 0.0625f);
            b.z = f2bf(acc.z * 0.0625f); b.w = f2bf(acc.w * 0.0625f);
            *(ushort4*)&sA[r * A_LD + c * 4] = b;
        }
        __syncthreads();
        f32x4 acc0 = {0.f, 0.f, 0.f, 0.f}, acc1 = {0.f, 0.f, 0.f, 0.f};
        #pragma unroll
        for (int kt = 0; kt < 4; ++kt) {
            const int k0 = kt * 32 + qd * 8;
            bf16x8 a  = *(const bf16x8*)&sA[ln * A_LD + k0];
            bf16x8 bb0 = *(const bf16x8*)&sWt[n0 * WT_LD + k0];
            bf16x8 bb1 = *(const bf16x8*)&sWt[n1 * WT_LD + k0];
            acc0 = __builtin_amdgcn_mfma_f32_16x16x32_bf16(a, bb0, acc0, 0, 0, 0);
            acc1 = __builtin_amdgcn_mfma_f32_16x16x32_bf16(a, bb1, acc1, 0, 0, 0);
        }
        #pragma unroll
        for (int ri = 0; ri < 4; ++ri) {
            const int row = i0 + qd * 4 + ri;
            float v0 = acc0[ri], v1 = acc1[ri];
            out[row * FEAT + n0] = v0;
            out[row * FEAT + n1] = v1;
            s1a += v0; s2a += v0 * v0;
            s1b += v1; s2b += v1 * v1;
        }
    }
    s1a += __shfl_down(s1a, 32); s1a += __shfl_down(s1a, 16);
    s2a += __shfl_down(s2a, 32); s2a += __shfl_down(s2a, 16);
    s1b += __shfl_down(s1b, 32); s1b += __shfl_down(s1b, 16);
    s2b += __shfl_down(s2b, 32); s2b += __shfl_down(s2b, 16);
    if (qd == 0) {
        atomicAdd(&gstats[n0], s1a);
        atomicAdd(&gstats[FEAT + n0], s2a);
        atomicAdd(&gstats[n1], s1b);
        atomicAdd(&gstats[FEAT + n1], s2b);
    }
}

extern "C" void kernel_launch(void* const* d_in, const int* in_sizes, int n_in,
                              void* d_out, int out_size, void* d_ws, size_t ws_size,
                              hipStream_t stream) {
    const float* raw   = (const float*)d_in[0];
    const float* W     = (const float*)d_in[1];
    const float* gamma = (const float*)d_in[2];
    const float* beta  = (const float*)d_in[3];
    const int*   idx   = (const int*)d_in[4];
    float* out = (float*)d_out;

    char* ws = (char*)d_ws;
    float* gstats = (float*)(ws + OFF_STATS);

    if (ws_size >= WS_NEEDED) {
        unsigned short* Wt   = (unsigned short*)(ws + OFF_WT);
        unsigned short* rawh = (unsigned short*)(ws + OFF_RAWH);
        unsigned short* nf   = (unsigned short*)(ws + OFF_NF);
        enc_conv<<<2048, 256, 0, stream>>>(raw, W, rawh, Wt, gstats);
        enc_gather<<<3125, 256, 0, stream>>>(rawh, idx, nf);
        enc_mm<<<782, 256, 0, stream>>>(nf, Wt, out, gstats);
        enc_bn<<<1024, 256, 0, stream>>>(out, gstats, gamma, beta);
    } else {
        hipMemsetAsync(gstats, 0, 2 * FEAT * sizeof(float), stream);
        enc_gemm_f<<<1024, 256, 0, stream>>>(raw, W, idx, out, gstats);
        enc_bn<<<1024, 256, 0, stream>>>(out, gstats, gamma, beta);
    }
}

// Round 6
// 153.458 us; speedup vs baseline: 1.0682x; 1.0682x over previous
//
#include <hip/hip_runtime.h>
#include <hip/hip_bf16.h>
#include <hip/hip_fp16.h>

// Encoder: neigh_feats = mean(raw[idx], axis=1); x = nf @ W; BN(train); LeakyReLU(0.01)
// Inputs: raw[100000,128]f32, W[128,128]f32, gamma[128], beta[128], idx[50000,16]i32
// Output: [50000,128] f32
//
// R6: fused gather+GEMM with ZERO per-tile barriers. One wave owns a whole
// 16-row tile: gather(16 neighbors, f16 packed adds) -> private LDS slice
// (intra-wave DS ordering, no __syncthreads) -> A-frags -> 8 n-tiles of MFMA
// vs sWt (staged once; barrier only at kernel start) -> f32 out + reg stats.
// Stats flush via LDS once at kernel end (second & last barrier).
// Pipeline: enc_conv (f32->f16 + Wt + zero stats) -> enc_fused -> enc_bn.
// Harness floor is ~80us (256MiB ws re-poison + input restores) - untouchable.

#define NTOTAL 100000
#define FEAT   128
#define NB     50000
#define KNEI   16
#define NTILES (NB / 16)   // 3125

// ws layout
#define OFF_STATS 0
#define OFF_WT    1024
#define OFF_RAWH  33792
#define WS_NEEDED (OFF_RAWH + 25600000)   // 25.6 MB rawh

typedef float f32x4 __attribute__((ext_vector_type(4)));
typedef short bf16x8 __attribute__((ext_vector_type(8)));
typedef _Float16 f16x8 __attribute__((ext_vector_type(8)));

#define ALD 136   // f16 elems per LDS row (272 B): 16B-aligned, 2-way banks (free)

__device__ __forceinline__ unsigned short f2bf(float f) {
    union { float f; unsigned u; } v; v.f = f;
    unsigned r = v.u + 0x7FFF + ((v.u >> 16) & 1);
    return (unsigned short)(r >> 16);
}
__device__ __forceinline__ unsigned h2add(unsigned a, unsigned b) {
    union { unsigned u; __half2 h; } x, y, r;
    x.u = a; y.u = b; r.h = __hadd2(x.h, y.h);
    return r.u;
}
__device__ __forceinline__ unsigned h2scale16(unsigned a) {   // * 0.0625 packed
    union { unsigned u; __half2 h; } x, c, r;
    x.u = a; c.u = 0x2C002C00u;
    r.h = __hmul2(x.h, c.h);
    return r.u;
}

// ---- conv: raw f32 -> f16 rows, W -> Wt f16 transposed (Wt[n*128+k]=W[k][n]) ---
__global__ __launch_bounds__(256) void enc_conv(
    const float* __restrict__ raw, const float* __restrict__ W,
    unsigned short* __restrict__ rawh, unsigned short* __restrict__ Wt,
    float* __restrict__ gstats)
{
    const int t = threadIdx.x;
    if (blockIdx.x < 64) {
        int e = blockIdx.x * 256 + t;     // 0..16383
        int n = e >> 7, k = e & 127;
        union { unsigned short s; __half h; } c; c.h = __float2half(W[k * FEAT + n]);
        Wt[e] = c.s;
    }
    if (blockIdx.x == 64 && t < 2 * FEAT) gstats[t] = 0.f;

    const float4* raw4 = (const float4*)raw;
    uint2* rh = (uint2*)rawh;
    const int NQ = NTOTAL * FEAT / 4;     // 3.2M
    for (int e = blockIdx.x * 256 + t; e < NQ; e += gridDim.x * 256) {
        float4 v = raw4[e];
        union { unsigned u; __half2 h; } lo, hi;
        lo.h = __float22half2_rn(make_float2(v.x, v.y));
        hi.h = __float22half2_rn(make_float2(v.z, v.w));
        uint2 o; o.x = lo.u; o.y = hi.u;
        rh[e] = o;
    }
}

// ---- fused: per-wave tile ownership, no per-tile barriers ----------------------
__global__ __launch_bounds__(256, 3) void enc_fused(
    const unsigned short* __restrict__ rawh, const unsigned short* __restrict__ Wt,
    const int* __restrict__ idx, float* __restrict__ out,
    float* __restrict__ gstats)
{
    __shared__ unsigned short sWt[128 * ALD];      // 34816 B, shared by all waves
    __shared__ unsigned short sA[4 * 16 * ALD];    // 17408 B, 4352 B per wave
    __shared__ float sStats[2 * FEAT];             //  1024 B

    const int t = threadIdx.x;
    const int lane = t & 63;
    const int wv = t >> 6;
    const int ln = lane & 15;   // = gather chunk c; = MFMA col-in-tile
    const int qd = lane >> 4;   // = gather row-group s; = MFMA quad

    // Stage Wt (f16, n-major) into padded LDS. 2048 16B chunks, coalesced.
    #pragma unroll
    for (int i = 0; i < 8; ++i) {
        int ch = t + i * 256;
        int n = ch >> 4, c4 = ch & 15;
        *(uint4*)&sWt[n * ALD + c4 * 8] = *(const uint4*)&Wt[n * 128 + c4 * 8];
    }
    sStats[t] = 0.f;           // t < 256 == 2*FEAT
    __syncthreads();           // barrier #1 (kernel start)

    unsigned short* sAw = &sA[wv * 16 * ALD];   // this wave's private slice

    float s1[8], s2[8];
    #pragma unroll
    for (int nt = 0; nt < 8; ++nt) { s1[nt] = 0.f; s2[nt] = 0.f; }

    for (int tile = blockIdx.x * 4 + wv; tile < NTILES; tile += gridDim.x * 4) {
        const int i0 = tile * 16;

        // This wave's 256 indices: 64 lanes x int4, one coalesced 1KB load.
        int iva[4];
        *(int4*)iva = ((const int4*)idx)[tile * 64 + lane];

        // Gather+mean: lane handles rows {qd, qd+4, qd+8, qd+12}, 16B chunk ln.
        // Per row: 16 loads issued back-to-back (16 outstanding uint4/lane).
        #pragma unroll
        for (int i = 0; i < 4; ++i) {
            const int r = qd + i * 4;
            uint4 v[16];
            #pragma unroll
            for (int k = 0; k < KNEI; ++k) {
                int ik = __shfl(iva[k & 3], r * 4 + (k >> 2));   // idx[(i0+r)*16+k]
                unsigned off = (unsigned)ik * FEAT + ln * 8;     // f16 elems
                v[k] = *(const uint4*)&rawh[off];
            }
            #pragma unroll
            for (int st = 8; st >= 1; st >>= 1) {
                #pragma unroll
                for (int k = 0; k < 8; ++k) {
                    if (k < st) {
                        v[k].x = h2add(v[k].x, v[k + st].x);
                        v[k].y = h2add(v[k].y, v[k + st].y);
                        v[k].z = h2add(v[k].z, v[k + st].z);
                        v[k].w = h2add(v[k].w, v[k + st].w);
                    }
                }
            }
            uint4 o;
            o.x = h2scale16(v[0].x); o.y = h2scale16(v[0].y);
            o.z = h2scale16(v[0].z); o.w = h2scale16(v[0].w);
            *(uint4*)&sAw[r * ALD + ln * 8] = o;
        }

        // Intra-wave LDS RAW: per-wave DS ops are processed in order; explicit
        // wait for safety (cross-lane visibility of the writes above).
        __asm__ __volatile__("s_waitcnt lgkmcnt(0)");

        // A-frags: lane ln = row, k = kt*32 + qd*8 + j.
        f16x8 a[4];
        #pragma unroll
        for (int kt = 0; kt < 4; ++kt)
            a[kt] = *(const f16x8*)&sAw[ln * ALD + kt * 32 + qd * 8];

        // MFMA over all 8 n-tiles (wave owns the full 128-col output row block).
        f32x4 acc[8];
        #pragma unroll
        for (int nt = 0; nt < 8; ++nt) acc[nt] = (f32x4){0.f, 0.f, 0.f, 0.f};
        #pragma unroll
        for (int nt = 0; nt < 8; ++nt) {
            #pragma unroll
            for (int kt = 0; kt < 4; ++kt) {
                f16x8 b = *(const f16x8*)&sWt[(nt * 16 + ln) * ALD + kt * 32 + qd * 8];
                acc[nt] = __builtin_amdgcn_mfma_f32_16x16x32_f16(a[kt], b, acc[nt], 0, 0, 0);
            }
        }

        // Epilogue: C/D layout col=ln, row=qd*4+ri. f32 store + stats in regs.
        #pragma unroll
        for (int nt = 0; nt < 8; ++nt) {
            const int col = nt * 16 + ln;
            #pragma unroll
            for (int ri = 0; ri < 4; ++ri) {
                const int row = i0 + qd * 4 + ri;
                float v = acc[nt][ri];
                out[row * FEAT + col] = v;
                s1[nt] += v; s2[nt] += v * v;
            }
        }
    }

    // Stats: reduce over the 4 lanes sharing each column, then LDS, then global.
    #pragma unroll
    for (int nt = 0; nt < 8; ++nt) {
        s1[nt] += __shfl_down(s1[nt], 32); s1[nt] += __shfl_down(s1[nt], 16);
        s2[nt] += __shfl_down(s2[nt], 32); s2[nt] += __shfl_down(s2[nt], 16);
    }
    if (qd == 0) {
        #pragma unroll
        for (int nt = 0; nt < 8; ++nt) {
            atomicAdd(&sStats[nt * 16 + ln], s1[nt]);
            atomicAdd(&sStats[FEAT + nt * 16 + ln], s2[nt]);
        }
    }
    __syncthreads();           // barrier #2 (kernel end)
    atomicAdd(&gstats[t], sStats[t]);   // 256 global atomics per block
}

// ---- bn: in-place BN + LeakyReLU on f32 out ------------------------------------
__global__ __launch_bounds__(256) void enc_bn(
    float* __restrict__ out, const float* __restrict__ gstats,
    const float* __restrict__ gamma, const float* __restrict__ beta)
{
    __shared__ float sScale[FEAT], sShift[FEAT];
    const int t = threadIdx.x;
    if (t < FEAT) {
        float s1 = gstats[t], s2 = gstats[FEAT + t];
        float mean = s1 * (1.0f / NB);
        float var = s2 * (1.0f / NB) - mean * mean;
        float sc = gamma[t] * rsqrtf(var + 1e-5f);
        sScale[t] = sc;
        sShift[t] = beta[t] - mean * sc;
    }
    __syncthreads();
    const int f4 = (t & 31) * 4;    // thread-invariant feature quad
    const float4 sc = *(const float4*)&sScale[f4];
    const float4 sh = *(const float4*)&sShift[f4];
    const int total4 = NB * FEAT / 4;
    float4* o4 = (float4*)out;
    for (int e = blockIdx.x * 256 + t; e < total4; e += gridDim.x * 256) {
        float4 v = o4[e];
        float4 r; float y;
        y = v.x * sc.x + sh.x; r.x = (y >= 0.f) ? y : 0.01f * y;
        y = v.y * sc.y + sh.y; r.y = (y >= 0.f) ? y : 0.01f * y;
        y = v.z * sc.z + sh.z; r.z = (y >= 0.f) ? y : 0.01f * y;
        y = v.w * sc.w + sh.w; r.w = (y >= 0.f) ? y : 0.01f * y;
        o4[e] = r;
    }
}

// ======================= fallback (f32 path, R1-proven) =========================
#define WT_LD 136
#define A_LD  136
__global__ __launch_bounds__(256, 4) void enc_gemm_f(
    const float* __restrict__ raw, const float* __restrict__ W,
    const int* __restrict__ idx, float* __restrict__ out,
    float* __restrict__ gstats)
{
    __shared__ unsigned short sWt[128 * WT_LD];
    __shared__ unsigned short sA2[16 * A_LD];
    __shared__ int sidx[256];
    const int t = threadIdx.x;
    #pragma unroll 4
    for (int i = 0; i < 64; ++i) {
        int e = t + i * 256;
        int f = e >> 7, n = e & 127;
        sWt[n * WT_LD + f] = f2bf(W[e]);
    }
    const int lane = t & 63, wv = t >> 6, ln = lane & 15, qd = lane >> 4;
    const int c = t & 31, g = t >> 5;
    const int n0 = wv * 32 + ln, n1 = n0 + 16;
    float s1a = 0.f, s2a = 0.f, s1b = 0.f, s2b = 0.f;
    const float4* raw4 = (const float4*)raw;
    for (int tile = blockIdx.x; tile < NTILES; tile += gridDim.x) {
        const int i0 = tile * 16;
        __syncthreads();
        sidx[t] = idx[i0 * KNEI + t];
        __syncthreads();
        #pragma unroll
        for (int rr = 0; rr < 2; ++rr) {
            const int r = g * 2 + rr;
            const int* ip = &sidx[r * KNEI];
            float4 acc = {0.f, 0.f, 0.f, 0.f};
            #pragma unroll
            for (int k = 0; k < KNEI; ++k) {
                float4 v = raw4[(size_t)ip[k] * 32 + c];
                acc.x += v.x; acc.y += v.y; acc.z += v.z; acc.w += v.w;
            }
            ushort4 b;
            b.x = f2bf(acc.x * 0.0625f); b.y = f2bf(acc.y * 0.0625f);
            b.z = f2bf(acc.z * 0.0625f); b.w = f2bf(acc.w * 0.0625f);
            *(ushort4*)&sA2[r * A_LD + c * 4] = b;
        }
        __syncthreads();
        f32x4 acc0 = {0.f, 0.f, 0.f, 0.f}, acc1 = {0.f, 0.f, 0.f, 0.f};
        #pragma unroll
        for (int kt = 0; kt < 4; ++kt) {
            const int k0 = kt * 32 + qd * 8;
            bf16x8 aa  = *(const bf16x8*)&sA2[ln * A_LD + k0];
            bf16x8 bb0 = *(const bf16x8*)&sWt[n0 * WT_LD + k0];
            bf16x8 bb1 = *(const bf16x8*)&sWt[n1 * WT_LD + k0];
            acc0 = __builtin_amdgcn_mfma_f32_16x16x32_bf16(aa, bb0, acc0, 0, 0, 0);
            acc1 = __builtin_amdgcn_mfma_f32_16x16x32_bf16(aa, bb1, acc1, 0, 0, 0);
        }
        #pragma unroll
        for (int ri = 0; ri < 4; ++ri) {
            const int row = i0 + qd * 4 + ri;
            float v0 = acc0[ri], v1 = acc1[ri];
            out[row * FEAT + n0] = v0;
            out[row * FEAT + n1] = v1;
            s1a += v0; s2a += v0 * v0;
            s1b += v1; s2b += v1 * v1;
        }
    }
    s1a += __shfl_down(s1a, 32); s1a += __shfl_down(s1a, 16);
    s2a += __shfl_down(s2a, 32); s2a += __shfl_down(s2a, 16);
    s1b += __shfl_down(s1b, 32); s1b += __shfl_down(s1b, 16);
    s2b += __shfl_down(s2b, 32); s2b += __shfl_down(s2b, 16);
    if (qd == 0) {
        atomicAdd(&gstats[n0], s1a);
        atomicAdd(&gstats[FEAT + n0], s2a);
        atomicAdd(&gstats[n1], s1b);
        atomicAdd(&gstats[FEAT + n1], s2b);
    }
}

extern "C" void kernel_launch(void* const* d_in, const int* in_sizes, int n_in,
                              void* d_out, int out_size, void* d_ws, size_t ws_size,
                              hipStream_t stream) {
    const float* raw   = (const float*)d_in[0];
    const float* W     = (const float*)d_in[1];
    const float* gamma = (const float*)d_in[2];
    const float* beta  = (const float*)d_in[3];
    const int*   idx   = (const int*)d_in[4];
    float* out = (float*)d_out;

    char* ws = (char*)d_ws;
    float* gstats = (float*)(ws + OFF_STATS);

    if (ws_size >= WS_NEEDED) {
        unsigned short* Wt   = (unsigned short*)(ws + OFF_WT);
        unsigned short* rawh = (unsigned short*)(ws + OFF_RAWH);
        enc_conv<<<2048, 256, 0, stream>>>(raw, W, rawh, Wt, gstats);
        enc_fused<<<768, 256, 0, stream>>>(rawh, Wt, idx, out, gstats);
        enc_bn<<<1024, 256, 0, stream>>>(out, gstats, gamma, beta);
    } else {
        hipMemsetAsync(gstats, 0, 2 * FEAT * sizeof(float), stream);
        enc_gemm_f<<<1024, 256, 0, stream>>>(raw, W, idx, out, gstats);
        enc_bn<<<1024, 256, 0, stream>>>(out, gstats, gamma, beta);
    }
}